// Round 4
// baseline (326.792 us; speedup 1.0000x reference)
//
#include <hip/hip_runtime.h>
#include <hip/hip_bf16.h>

// BandSplit on MI355X — round 5.
// R4 post-mortem: prediction matched (334->317 via phase-1 load batching) =>
// main is phase-1 issue/latency bound. Remaining waste: each (tc,b) x-slice
// is normalized 4x (once per q-sibling), ~27 scattered vmem + band VALU each.
// This round: NEW norm_kernel writes the exact bf16 LDS tile image (33,024 B,
// [16][1032], zero-padded) to ws once per (tc,b); main's phase 1 becomes a
// linear 33 KB coalesced copy (9 uint4 loads, no addressing math, no zeroing).
// ws needs 393,216 + 33,288,192 B; poison-fill evidence (992,000 KB/iter)
// says the arena is ~1 GB. Guarded: falls back to the R4 fused main if small.
//
// ws layout (f32 unless noted):
//   sA  : float[16][1024]   rsigma*gn_w at K-padded positions (band i -> kp=32i)
//   sB  : float[16][1024]   gn_b - mu*rsigma*gn_w
//   wf  : ushort[32*8*64*8] fc_w as bf16 in MFMA B-fragment order, zero padded
//   xnG : ushort[1008][16512]  normalized bf16 tiles, tile = b*63 + tc

typedef short short8 __attribute__((ext_vector_type(8)));
typedef float floatx4 __attribute__((ext_vector_type(4)));

__device__ __forceinline__ unsigned short f2bf(float f) {
  unsigned int u = __float_as_uint(f);
  u = (u + 0x7fffu + ((u >> 16) & 1u)) >> 16;  // RNE
  return (unsigned short)u;
}

// BANDS = [2, 3x10, 8x12, 16x7, 17]; c = 2*band; K padded to 32 per band
// (band 30: c=34 -> ksteps 30 and 31).
__device__ __forceinline__ int band_of_f(int f) {
  if (f < 2) return 0;
  if (f < 32) return 1 + (f - 2) / 3;
  if (f < 128) return 11 + (f - 32) / 8;
  if (f < 240) return 23 + (f - 128) / 16;
  return 30;
}
__device__ __forceinline__ int f0_of_band(int i) {
  if (i == 0) return 0;
  if (i <= 10) return 2 + 3 * (i - 1);
  if (i <= 22) return 32 + 8 * (i - 11);
  if (i <= 29) return 128 + 16 * (i - 23);
  return 240;
}
__device__ __forceinline__ int c_of_band(int i) {
  if (i == 0) return 4;
  if (i <= 10) return 6;
  if (i <= 22) return 16;
  if (i <= 29) return 32;
  return 34;
}
__device__ __forceinline__ int bw_of_band(int i) {
  if (i == 0) return 2;
  if (i <= 10) return 3;
  if (i <= 22) return 8;
  if (i <= 29) return 16;
  return 17;
}

// ---------------------------------------------------------------------------
// Kernel 1 (fused): blocks 0..495 = per-(band,batch) GroupNorm stats folded
// into per-channel affine sA/sB; blocks 496..559 = fc_w (f32) -> bf16 MFMA
// B-fragment order. Independent work, one launch.
// ---------------------------------------------------------------------------
__global__ __launch_bounds__(256) void prep_kernel(
    const float* __restrict__ x,
    const float* __restrict__ gn_w,
    const float* __restrict__ gn_b,
    const float* __restrict__ fc_w,
    float* __restrict__ sA, float* __restrict__ sB,
    unsigned short* __restrict__ wf) {
  const int blk = blockIdx.x;
  const int tid = threadIdx.x;
  __shared__ float redS[4], redQ[4];
  __shared__ float musig[2];

  if (blk >= 496) {
    // ---- wprep part: flat short8 index gid = ks*512 + ot*64 + lane;
    // element j = Wp[kp = ks*32 + (lane>>4)*8 + j][o = ot*16 + (lane&15)].
    const int gid = (blk - 496) * 256 + tid;  // 0..16383
    const int ks = gid >> 9;
    const int rem = gid & 511;
    const int ot = rem >> 6;
    const int l = rem & 63;
    const int o = ot * 16 + (l & 15);
    const int kbase = ks * 32 + ((l >> 4) << 3);
    short8 v;
#pragma unroll
    for (int j = 0; j < 8; ++j) {
      int kp = kbase + j;
      int i = (kp >= 960) ? 30 : (kp >> 5);
      int cidx = kp - (i << 5);
      int c = c_of_band(i);
      unsigned short w =
          (cidx < c) ? f2bf(fc_w[(i * 128 + o) * 34 + cidx]) : (unsigned short)0;
      v[j] = (short)w;
    }
    ((short8*)wf)[gid] = v;
    return;
  }

  // ---- stats part
  const int i = blk % 31;  // band
  const int b = blk / 31;  // batch
  const int bw = bw_of_band(i);
  const int f0 = f0_of_band(i);
  // slab: x[b, f0:f0+bw, :, :] -> contiguous bw*2000 f32; start*4 % 16 == 0
  const long start = ((long)(b * 257 + f0)) * 2000;
  const float4* p4 = (const float4*)(x + start);
  const int nchunk = bw * 500;  // 4 f32 per chunk

  float s = 0.f, sq = 0.f;
  int e = tid;
  for (; e + 768 < nchunk; e += 1024) {
    float4 w0 = p4[e];
    float4 w1 = p4[e + 256];
    float4 w2 = p4[e + 512];
    float4 w3 = p4[e + 768];
    s += (w0.x + w0.y + w0.z + w0.w) + (w1.x + w1.y + w1.z + w1.w) +
         (w2.x + w2.y + w2.z + w2.w) + (w3.x + w3.y + w3.z + w3.w);
    sq += (w0.x * w0.x + w0.y * w0.y + w0.z * w0.z + w0.w * w0.w) +
          (w1.x * w1.x + w1.y * w1.y + w1.z * w1.z + w1.w * w1.w) +
          (w2.x * w2.x + w2.y * w2.y + w2.z * w2.z + w2.w * w2.w) +
          (w3.x * w3.x + w3.y * w3.y + w3.z * w3.z + w3.w * w3.w);
  }
  for (; e < nchunk; e += 256) {
    float4 v = p4[e];
    s += v.x + v.y + v.z + v.w;
    sq += v.x * v.x + v.y * v.y + v.z * v.z + v.w * v.w;
  }
#pragma unroll
  for (int off = 32; off > 0; off >>= 1) {
    s += __shfl_down(s, off);
    sq += __shfl_down(sq, off);
  }
  if ((tid & 63) == 0) { redS[tid >> 6] = s; redQ[tid >> 6] = sq; }
  __syncthreads();
  if (tid == 0) {
    float S = redS[0] + redS[1] + redS[2] + redS[3];
    float Q = redQ[0] + redQ[1] + redQ[2] + redQ[3];
    float cnt = (float)(bw * 2000);
    float mu = S / cnt;
    float var = Q / cnt - mu * mu;
    musig[0] = mu;
    musig[1] = rsqrtf(var + 1e-5f);
  }
  __syncthreads();
  const int c = c_of_band(i);
  if (tid < c) {
    float mu = musig[0], rs = musig[1];
    float gw = gn_w[i * 34 + tid];
    float gb = gn_b[i * 34 + tid];
    float a = rs * gw;
    int kp = i * 32 + tid;  // band 30 spills into kstep 31
    sA[(b << 10) + kp] = a;
    sB[(b << 10) + kp] = gb - mu * a;
  }
}

// ---------------------------------------------------------------------------
// Kernel 2: normalize once per (tc,b) tile. Builds the exact LDS tile image
// main consumes — bf16 [16][1032], zero-padded — then streams it to xnG with
// fully-coalesced uint4 stores. Math bit-identical to the old fused phase 1.
// ---------------------------------------------------------------------------
__global__ __launch_bounds__(256, 4) void norm_kernel(
    const float* __restrict__ x,
    const float* __restrict__ sA, const float* __restrict__ sB,
    unsigned short* __restrict__ xnG) {
  const int tc = blockIdx.x;  // 0..62
  const int b = blockIdx.y;   // 0..15
  const int t0 = tc * 16;
  const int tid = threadIdx.x;

  __shared__ __align__(16) unsigned char lds_raw[16 * 1032 * 2];  // 33,024 B
  unsigned short(*xn)[1032] = (unsigned short(*)[1032])lds_raw;

  // zero (pads must be 0 so MFMA K-padding contributes nothing)
  for (int e = tid; e < 2064; e += 256)
    ((uint4*)lds_raw)[e] = make_uint4(0u, 0u, 0u, 0u);
  __syncthreads();

  // float4 element d = 0..2047: f = d>>3, kpair = d&7 -> t = t0 + 2*kpair,
  // covers t and t+1 (t even => never straddles the t=999 edge).
  const float4* xq = (const float4*)(x + (long)b * 514000 + (long)t0 * 2);
  const float* sAb = sA + (b << 10);
  const float* sBb = sB + (b << 10);
#pragma unroll
  for (int half = 0; half < 2; ++half) {
    float4 xv[4];
    float2 av[4], sv[4];
    int row[4], kps[4];
    bool val[4];
#pragma unroll
    for (int j = 0; j < 4; ++j) {
      int d = tid + (half * 4 + j) * 256;  // 0..2047
      int f = d >> 3;
      int kpair = d & 7;
      int i = band_of_f(f);
      int kp = (i << 5) + 2 * (f - f0_of_band(i));
      bool v = (t0 + 2 * kpair < 1000);
      row[j] = 2 * kpair; kps[j] = kp; val[j] = v;
      if (v) {
        xv[j] = xq[f * 500 + kpair];
        av[j] = *(const float2*)(sAb + kp);
        sv[j] = *(const float2*)(sBb + kp);
      }
    }
#pragma unroll
    for (int j = 0; j < 4; ++j) {
      if (val[j]) {
        unsigned int r0 = f2bf(xv[j].x * av[j].x + sv[j].x);
        unsigned int r1 = f2bf(xv[j].y * av[j].y + sv[j].y);
        unsigned int r2 = f2bf(xv[j].z * av[j].x + sv[j].x);
        unsigned int r3 = f2bf(xv[j].w * av[j].y + sv[j].y);
        *(unsigned int*)&xn[row[j]][kps[j]] = r0 | (r1 << 16);  // kp even
        *(unsigned int*)&xn[row[j] + 1][kps[j]] = r2 | (r3 << 16);
      }
    }
  }
  // tail: f = 256 (band 30, cidx 32/33 -> kp 992), 8 float4 by tid<8
  if (tid < 8 && t0 + 2 * tid < 1000) {
    float4 v = xq[256 * 500 + tid];
    float2 av = *(const float2*)(sAb + 992);
    float2 sv = *(const float2*)(sBb + 992);
    unsigned int r0 = f2bf(v.x * av.x + sv.x);
    unsigned int r1 = f2bf(v.y * av.y + sv.y);
    unsigned int r2 = f2bf(v.z * av.x + sv.x);
    unsigned int r3 = f2bf(v.w * av.y + sv.y);
    *(unsigned int*)&xn[2 * tid][992] = r0 | (r1 << 16);
    *(unsigned int*)&xn[2 * tid + 1][992] = r2 | (r3 << 16);
  }
  __syncthreads();

  // stream tile to global: 2064 uint4, coalesced
  uint4* dst = (uint4*)(xnG + (long)(b * 63 + tc) * 16512);
#pragma unroll
  for (int k = 0; k < 8; ++k)
    dst[tid + k * 256] = ((const uint4*)lds_raw)[tid + k * 256];
  if (tid < 16) dst[2048 + tid] = ((const uint4*)lds_raw)[2048 + tid];
}

// ---------------------------------------------------------------------------
// Kernel 3: main. Grid = (tc 64 [63 + 1 pad], q 4, b 16); tc fastest so the
// 4 q-siblings of a (tc,b) pair land on the same XCD (L2-hot tile).
// Phase 1: linear 33 KB tile copy — 9 coalesced uint4 loads + LDS writes per
//          thread, zero addressing VALU, no zero-init (tile carries pads).
// Phase 2: all MFMAs, accumulators stay in registers.
// Phase 3: two half passes (ot = 0,1): deposit 16x496 f32 into the SAME LDS
//          (union with xn), then coalesced dwordx4 stores of 496-f32 runs.
// LDS = 33,024 B -> 4 blocks/CU with __launch_bounds__(256,4).
// ---------------------------------------------------------------------------
__global__ __launch_bounds__(256, 4) void main_kernel(
    const unsigned short* __restrict__ xnG,
    const unsigned short* __restrict__ wf,
    const float* __restrict__ fc_b,
    float* __restrict__ out) {
  const int tc = blockIdx.x;  // 0..63 (63 is grid pad)
  const int q = blockIdx.y;   // 0..3  (o-quarter)
  const int b = blockIdx.z;   // 0..15
  const int t0 = tc * 16;
  if (t0 >= 1000) return;  // uniform pad-block exit, before any barrier
  const int tid = threadIdx.x;

  __shared__ __align__(16) unsigned char lds_raw[16 * 1032 * 2];  // 33,024 B
  unsigned short(*xn)[1032] = (unsigned short(*)[1032])lds_raw;
  float(*stage)[496] = (float(*)[496])lds_raw;  // 16*496*4 = 31,744 B

  const int wv = tid >> 6;
  const int l = tid & 63;
  const int quad = l >> 4;
  const int n = l & 15;

  // fc_b bias preload: 16 independent 4B loads, issued alongside the tile
  // copy loads so their latency overlaps. Static indexing only.
  float bias[8][2];
#pragma unroll
  for (int it = 0; it < 8; ++it) {
    const int band = wv + it * 4;
    if (band >= 31) break;
#pragma unroll
    for (int ot = 0; ot < 2; ++ot)
      bias[it][ot] = fc_b[band * 128 + (((q << 1) | ot) << 4) + n];
  }

  // Phase 1: linear tile copy, 2064 uint4 (8 full rounds + 16-thread tail).
  // All 9 loads issue back-to-back before any use.
  const uint4* src = (const uint4*)(xnG + (long)(b * 63 + tc) * 16512);
  uint4 tmp[8];
#pragma unroll
  for (int k = 0; k < 8; ++k) tmp[k] = src[tid + k * 256];
  uint4 tail;
  if (tid < 16) tail = src[2048 + tid];
#pragma unroll
  for (int k = 0; k < 8; ++k) ((uint4*)lds_raw)[tid + k * 256] = tmp[k];
  if (tid < 16) ((uint4*)lds_raw)[2048 + tid] = tail;
  __syncthreads();

  // Phase 2: MFMAs; wave wv handles bands wv, wv+4, ... (acc in registers)
  floatx4 acc[8][2];
#pragma unroll
  for (int it = 0; it < 8; ++it) {
    const int band = wv + it * 4;
    if (band >= 31) break;
    const bool dbl = (band == 30);  // c=34 -> second kstep
    short8 a0 = *(const short8*)&xn[n][(band << 5) + (quad << 3)];
#pragma unroll
    for (int ot = 0; ot < 2; ++ot) {
      const int OT = (q << 1) | ot;
      float bv = bias[it][ot];
      floatx4 a = {bv, bv, bv, bv};
      short8 b0 = ((const short8*)wf)[(band * 8 + OT) * 64 + l];
      a = __builtin_amdgcn_mfma_f32_16x16x32_bf16(a0, b0, a, 0, 0, 0);
      if (dbl) {
        short8 a1 = *(const short8*)&xn[n][992 + (quad << 3)];
        short8 b1 = ((const short8*)wf)[(31 * 8 + OT) * 64 + l];
        a = __builtin_amdgcn_mfma_f32_16x16x32_bf16(a1, b1, a, 0, 0, 0);
      }
      acc[it][ot] = a;
    }
  }
  __syncthreads();  // all xn reads done; safe to overwrite union

  // Phase 3: two half passes over ot. Each pass deposits D fragments into
  // stage[m][n*31 + band] (m = quad*4 + r; D row(m)=quad*4+r, col=lane&15,
  // m89/m91-verified) then stores 16 rows x 496 f32, contiguous in out at
  // (b*1000+t)*3968 + q*992 + ot*496 (uint4-aligned, 64B-aligned rows).
#pragma unroll
  for (int ot = 0; ot < 2; ++ot) {
    if (ot) __syncthreads();  // pass-0 store reads done before overwrite
#pragma unroll
    for (int it = 0; it < 8; ++it) {
      const int band = wv + it * 4;
      if (band >= 31) break;
#pragma unroll
      for (int r = 0; r < 4; ++r)
        stage[(quad << 2) + r][n * 31 + band] = acc[it][ot][r];
    }
    __syncthreads();
    for (int e = tid; e < 16 * 124; e += 256) {
      int m = e / 124;
      int d = e - m * 124;
      int t = t0 + m;
      if (t < 1000) {
        uint4 v = ((const uint4*)&stage[m][0])[d];
        ((uint4*)out)[(long)(b * 1000 + t) * 992 + q * 248 + ot * 124 + d] = v;
      }
    }
  }
}

// ---------------------------------------------------------------------------
// Fallback main (R4 fused normalize) — used only if ws is too small for xnG.
// ---------------------------------------------------------------------------
__global__ __launch_bounds__(256, 4) void main_kernel_fb(
    const float* __restrict__ x,
    const float* __restrict__ sA, const float* __restrict__ sB,
    const unsigned short* __restrict__ wf,
    const float* __restrict__ fc_b,
    float* __restrict__ out) {
  const int tc = blockIdx.x;
  const int q = blockIdx.y;
  const int b = blockIdx.z;
  const int t0 = tc * 16;
  if (t0 >= 1000) return;
  const int tid = threadIdx.x;

  __shared__ __align__(16) unsigned char lds_raw[16 * 1032 * 2];
  unsigned short(*xn)[1032] = (unsigned short(*)[1032])lds_raw;
  float(*stage)[496] = (float(*)[496])lds_raw;

  const int wv = tid >> 6;
  const int l = tid & 63;
  const int quad = l >> 4;
  const int n = l & 15;

  float bias[8][2];
#pragma unroll
  for (int it = 0; it < 8; ++it) {
    const int band = wv + it * 4;
    if (band >= 31) break;
#pragma unroll
    for (int ot = 0; ot < 2; ++ot)
      bias[it][ot] = fc_b[band * 128 + (((q << 1) | ot) << 4) + n];
  }

  for (int e = tid; e < 2064; e += 256)
    ((uint4*)lds_raw)[e] = make_uint4(0u, 0u, 0u, 0u);
  __syncthreads();

  const float4* xq = (const float4*)(x + (long)b * 514000 + (long)t0 * 2);
  const float* sAb = sA + (b << 10);
  const float* sBb = sB + (b << 10);
#pragma unroll
  for (int half = 0; half < 2; ++half) {
    float4 xv[4];
    float2 av[4], sv[4];
    int row[4], kps[4];
    bool val[4];
#pragma unroll
    for (int j = 0; j < 4; ++j) {
      int d = tid + (half * 4 + j) * 256;
      int f = d >> 3;
      int kpair = d & 7;
      int i = band_of_f(f);
      int kp = (i << 5) + 2 * (f - f0_of_band(i));
      bool v = (t0 + 2 * kpair < 1000);
      row[j] = 2 * kpair; kps[j] = kp; val[j] = v;
      if (v) {
        xv[j] = xq[f * 500 + kpair];
        av[j] = *(const float2*)(sAb + kp);
        sv[j] = *(const float2*)(sBb + kp);
      }
    }
#pragma unroll
    for (int j = 0; j < 4; ++j) {
      if (val[j]) {
        unsigned int r0 = f2bf(xv[j].x * av[j].x + sv[j].x);
        unsigned int r1 = f2bf(xv[j].y * av[j].y + sv[j].y);
        unsigned int r2 = f2bf(xv[j].z * av[j].x + sv[j].x);
        unsigned int r3 = f2bf(xv[j].w * av[j].y + sv[j].y);
        *(unsigned int*)&xn[row[j]][kps[j]] = r0 | (r1 << 16);
        *(unsigned int*)&xn[row[j] + 1][kps[j]] = r2 | (r3 << 16);
      }
    }
  }
  if (tid < 8 && t0 + 2 * tid < 1000) {
    float4 v = xq[256 * 500 + tid];
    float2 av = *(const float2*)(sAb + 992);
    float2 sv = *(const float2*)(sBb + 992);
    unsigned int r0 = f2bf(v.x * av.x + sv.x);
    unsigned int r1 = f2bf(v.y * av.y + sv.y);
    unsigned int r2 = f2bf(v.z * av.x + sv.x);
    unsigned int r3 = f2bf(v.w * av.y + sv.y);
    *(unsigned int*)&xn[2 * tid][992] = r0 | (r1 << 16);
    *(unsigned int*)&xn[2 * tid + 1][992] = r2 | (r3 << 16);
  }
  __syncthreads();

  floatx4 acc[8][2];
#pragma unroll
  for (int it = 0; it < 8; ++it) {
    const int band = wv + it * 4;
    if (band >= 31) break;
    const bool dbl = (band == 30);
    short8 a0 = *(const short8*)&xn[n][(band << 5) + (quad << 3)];
#pragma unroll
    for (int ot = 0; ot < 2; ++ot) {
      const int OT = (q << 1) | ot;
      float bv = bias[it][ot];
      floatx4 a = {bv, bv, bv, bv};
      short8 b0 = ((const short8*)wf)[(band * 8 + OT) * 64 + l];
      a = __builtin_amdgcn_mfma_f32_16x16x32_bf16(a0, b0, a, 0, 0, 0);
      if (dbl) {
        short8 a1 = *(const short8*)&xn[n][992 + (quad << 3)];
        short8 b1 = ((const short8*)wf)[(31 * 8 + OT) * 64 + l];
        a = __builtin_amdgcn_mfma_f32_16x16x32_bf16(a1, b1, a, 0, 0, 0);
      }
      acc[it][ot] = a;
    }
  }
  __syncthreads();

#pragma unroll
  for (int ot = 0; ot < 2; ++ot) {
    if (ot) __syncthreads();
#pragma unroll
    for (int it = 0; it < 8; ++it) {
      const int band = wv + it * 4;
      if (band >= 31) break;
#pragma unroll
      for (int r = 0; r < 4; ++r)
        stage[(quad << 2) + r][n * 31 + band] = acc[it][ot][r];
    }
    __syncthreads();
    for (int e = tid; e < 16 * 124; e += 256) {
      int m = e / 124;
      int d = e - m * 124;
      int t = t0 + m;
      if (t < 1000) {
        uint4 v = ((const uint4*)&stage[m][0])[d];
        ((uint4*)out)[(long)(b * 1000 + t) * 992 + q * 248 + ot * 124 + d] = v;
      }
    }
  }
}

extern "C" void kernel_launch(void* const* d_in, const int* in_sizes, int n_in,
                              void* d_out, int out_size, void* d_ws, size_t ws_size,
                              hipStream_t stream) {
  const float* x = (const float*)d_in[0];
  const float* gn_w = (const float*)d_in[1];
  const float* gn_b = (const float*)d_in[2];
  const float* fc_w = (const float*)d_in[3];
  const float* fc_b = (const float*)d_in[4];
  float* out = (float*)d_out;

  float* sA = (float*)d_ws;
  float* sB = sA + 16 * 1024;
  unsigned short* wf = (unsigned short*)(sB + 16 * 1024);
  unsigned short* xnG = (unsigned short*)((char*)d_ws + 393216);
  const size_t need = 393216 + (size_t)1008 * 16512 * 2;  // 33,681,408 B

  prep_kernel<<<560, 256, 0, stream>>>(x, gn_w, gn_b, fc_w, sA, sB, wf);
  if (ws_size >= need) {
    norm_kernel<<<dim3(63, 16), 256, 0, stream>>>(x, sA, sB, xnG);
    main_kernel<<<dim3(64, 4, 16), 256, 0, stream>>>(xnG, wf, fc_b, out);
  } else {
    main_kernel_fb<<<dim3(64, 4, 16), 256, 0, stream>>>(x, sA, sB, wf, fc_b, out);
  }
}

// Round 5
// 317.327 us; speedup vs baseline: 1.0298x; 1.0298x over previous
//
#include <hip/hip_runtime.h>
#include <hip/hip_bf16.h>

// BandSplit on MI355X — round 6.
// R5 post-mortem: materializing xn REGRESSED (317->327): norm kernel's 66MB
// HBM round-trip (+15-20us) > main's phase-1 saving (~6-10us). Reverted.
// Lesson: phase-1 cost ~= redundant work per q-sibling, and moving it off-
// chip doesn't pay. Correct dedup: more output per tile-build. This round:
// o-HALVES instead of quarters — block=(tc,qh,b), 2016 blocks, acc[8][4]
// (128 VGPR, launch_bounds(256,3)), phase-1 redundancy 2x not 4x; plus
// packed sAB float4 table (1 load instead of 2 per x-float4; bit-identical).
//
// ws layout (f32 unless noted):
//   sAB : float[16][2048]   interleaved (a(2j),a(2j+1),s(2j),s(2j+1)) quads,
//                           a = rsigma*gn_w, s = gn_b - mu*rsigma*gn_w,
//                           at K-padded positions (band i -> kp=32i)
//   wf  : ushort[32*8*64*8] fc_w as bf16 in MFMA B-fragment order, 0-padded
// total 393,216 B (unchanged).

typedef short short8 __attribute__((ext_vector_type(8)));
typedef float floatx4 __attribute__((ext_vector_type(4)));

__device__ __forceinline__ unsigned short f2bf(float f) {
  unsigned int u = __float_as_uint(f);
  u = (u + 0x7fffu + ((u >> 16) & 1u)) >> 16;  // RNE
  return (unsigned short)u;
}

// BANDS = [2, 3x10, 8x12, 16x7, 17]; c = 2*band; K padded to 32 per band
// (band 30: c=34 -> ksteps 30 and 31).
__device__ __forceinline__ int band_of_f(int f) {
  if (f < 2) return 0;
  if (f < 32) return 1 + (f - 2) / 3;
  if (f < 128) return 11 + (f - 32) / 8;
  if (f < 240) return 23 + (f - 128) / 16;
  return 30;
}
__device__ __forceinline__ int f0_of_band(int i) {
  if (i == 0) return 0;
  if (i <= 10) return 2 + 3 * (i - 1);
  if (i <= 22) return 32 + 8 * (i - 11);
  if (i <= 29) return 128 + 16 * (i - 23);
  return 240;
}
__device__ __forceinline__ int c_of_band(int i) {
  if (i == 0) return 4;
  if (i <= 10) return 6;
  if (i <= 22) return 16;
  if (i <= 29) return 32;
  return 34;
}
__device__ __forceinline__ int bw_of_band(int i) {
  if (i == 0) return 2;
  if (i <= 10) return 3;
  if (i <= 22) return 8;
  if (i <= 29) return 16;
  return 17;
}

// ---------------------------------------------------------------------------
// Kernel 1 (fused): blocks 0..495 = per-(band,batch) GroupNorm stats folded
// into the packed sAB quads; blocks 496..559 = fc_w (f32) -> bf16 MFMA
// B-fragment order. Independent work, one launch.
// ---------------------------------------------------------------------------
__global__ __launch_bounds__(256) void prep_kernel(
    const float* __restrict__ x,
    const float* __restrict__ gn_w,
    const float* __restrict__ gn_b,
    const float* __restrict__ fc_w,
    float* __restrict__ sAB,
    unsigned short* __restrict__ wf) {
  const int blk = blockIdx.x;
  const int tid = threadIdx.x;
  __shared__ float redS[4], redQ[4];
  __shared__ float musig[2];

  if (blk >= 496) {
    // ---- wprep part: flat short8 index gid = ks*512 + ot*64 + lane;
    // element j = Wp[kp = ks*32 + (lane>>4)*8 + j][o = ot*16 + (lane&15)].
    const int gid = (blk - 496) * 256 + tid;  // 0..16383
    const int ks = gid >> 9;
    const int rem = gid & 511;
    const int ot = rem >> 6;
    const int l = rem & 63;
    const int o = ot * 16 + (l & 15);
    const int kbase = ks * 32 + ((l >> 4) << 3);
    short8 v;
#pragma unroll
    for (int j = 0; j < 8; ++j) {
      int kp = kbase + j;
      int i = (kp >= 960) ? 30 : (kp >> 5);
      int cidx = kp - (i << 5);
      int c = c_of_band(i);
      unsigned short w =
          (cidx < c) ? f2bf(fc_w[(i * 128 + o) * 34 + cidx]) : (unsigned short)0;
      v[j] = (short)w;
    }
    ((short8*)wf)[gid] = v;
    return;
  }

  // ---- stats part
  const int i = blk % 31;  // band
  const int b = blk / 31;  // batch
  const int bw = bw_of_band(i);
  const int f0 = f0_of_band(i);
  // slab: x[b, f0:f0+bw, :, :] -> contiguous bw*2000 f32; start*4 % 16 == 0
  const long start = ((long)(b * 257 + f0)) * 2000;
  const float4* p4 = (const float4*)(x + start);
  const int nchunk = bw * 500;  // 4 f32 per chunk

  float s = 0.f, sq = 0.f;
  int e = tid;
  for (; e + 768 < nchunk; e += 1024) {
    float4 w0 = p4[e];
    float4 w1 = p4[e + 256];
    float4 w2 = p4[e + 512];
    float4 w3 = p4[e + 768];
    s += (w0.x + w0.y + w0.z + w0.w) + (w1.x + w1.y + w1.z + w1.w) +
         (w2.x + w2.y + w2.z + w2.w) + (w3.x + w3.y + w3.z + w3.w);
    sq += (w0.x * w0.x + w0.y * w0.y + w0.z * w0.z + w0.w * w0.w) +
          (w1.x * w1.x + w1.y * w1.y + w1.z * w1.z + w1.w * w1.w) +
          (w2.x * w2.x + w2.y * w2.y + w2.z * w2.z + w2.w * w2.w) +
          (w3.x * w3.x + w3.y * w3.y + w3.z * w3.z + w3.w * w3.w);
  }
  for (; e < nchunk; e += 256) {
    float4 v = p4[e];
    s += v.x + v.y + v.z + v.w;
    sq += v.x * v.x + v.y * v.y + v.z * v.z + v.w * v.w;
  }
#pragma unroll
  for (int off = 32; off > 0; off >>= 1) {
    s += __shfl_down(s, off);
    sq += __shfl_down(sq, off);
  }
  if ((tid & 63) == 0) { redS[tid >> 6] = s; redQ[tid >> 6] = sq; }
  __syncthreads();
  if (tid == 0) {
    float S = redS[0] + redS[1] + redS[2] + redS[3];
    float Q = redQ[0] + redQ[1] + redQ[2] + redQ[3];
    float cnt = (float)(bw * 2000);
    float mu = S / cnt;
    float var = Q / cnt - mu * mu;
    musig[0] = mu;
    musig[1] = rsqrtf(var + 1e-5f);
  }
  __syncthreads();
  const int c = c_of_band(i);
  if (tid < c) {
    float mu = musig[0], rs = musig[1];
    float gw = gn_w[i * 34 + tid];
    float gb = gn_b[i * 34 + tid];
    float a = rs * gw;
    int kp = i * 32 + tid;  // band 30 spills into kstep 31
    // packed quad (a_even, a_odd, s_even, s_odd) at quad index kp>>1
    sAB[(b << 11) + ((kp >> 1) << 2) + (kp & 1)] = a;
    sAB[(b << 11) + ((kp >> 1) << 2) + 2 + (kp & 1)] = gb - mu * a;
  }
}

// ---------------------------------------------------------------------------
// Kernel 2: main. Grid = (tc 64 [63 + 1 pad], qh 2, b 16); tc fastest so the
// 2 qh-siblings of a (tc,b) pair differ by 64 = 0 mod 8 => same XCD.
// Each block builds the xn tile ONCE and produces an o-HALF (4 OT groups):
// Phase 1: x (f32) -> normalized bf16 [16][1032] in LDS; packed-sAB float4
//          gives 2 loads per x-float4 (was 3). Math bit-identical.
// Phase 2: 8 bands/wave x 4 OT MFMAs, acc[8][4] in registers (128 VGPR).
// Phase 3: four 1-OT passes: deposit 16x496 f32 into the SAME LDS (union
//          with xn — legal, all MFMAs done), then coalesced dwordx4 stores.
// LDS = 33,024 B; __launch_bounds__(256,3) -> 3 waves/SIMD (12 waves/CU).
// ---------------------------------------------------------------------------
__global__ __launch_bounds__(256, 3) void main_kernel(
    const float* __restrict__ x,
    const float* __restrict__ sAB,
    const unsigned short* __restrict__ wf,
    const float* __restrict__ fc_b,
    float* __restrict__ out) {
  const int tc = blockIdx.x;  // 0..63 (63 is grid pad)
  const int qh = blockIdx.y;  // 0..1  (o-half)
  const int b = blockIdx.z;   // 0..15
  const int t0 = tc * 16;
  if (t0 >= 1000) return;  // uniform pad-block exit, before any barrier
  const int tid = threadIdx.x;

  __shared__ __align__(16) unsigned char lds_raw[16 * 1032 * 2];  // 33,024 B
  unsigned short(*xn)[1032] = (unsigned short(*)[1032])lds_raw;
  float(*stage)[496] = (float(*)[496])lds_raw;  // 16*496*4 = 31,744 B

  const int wv = tid >> 6;
  const int l = tid & 63;
  const int quad = l >> 4;
  const int n = l & 15;

  // fc_b bias preload: 32 independent 4B loads issued before phase-1 so
  // their latency hides under the x-load round-trips; dies at acc-init.
  float bias[8][4];
#pragma unroll
  for (int it = 0; it < 8; ++it) {
    const int band = wv + it * 4;
    if (band >= 31) break;
#pragma unroll
    for (int p = 0; p < 4; ++p)
      bias[it][p] = fc_b[band * 128 + (((qh << 2) | p) << 4) + n];
  }

  // zero xn (pads must be 0 so MFMA K-padding contributes nothing)
  for (int e = tid; e < 2064; e += 256)
    ((uint4*)lds_raw)[e] = make_uint4(0u, 0u, 0u, 0u);
  __syncthreads();

  // Phase 1: x (f32) -> normalized bf16, layout [t_local][kp].
  // float4 element d = 0..2047: f = d>>3, kpair = d&7 -> t = t0 + 2*kpair,
  // covers t and t+1 (t even => never straddles the t=999 edge).
  // Packed sAB: quad (a_e, a_o, s_e, s_o) at index kp>>1 — one float4 load.
  const float4* xq = (const float4*)(x + (long)b * 514000 + (long)t0 * 2);
  const float4* sq = (const float4*)(sAB + (b << 11));
#pragma unroll
  for (int half = 0; half < 2; ++half) {
    float4 xv[4], ab[4];
    int row[4], kps[4];
    bool val[4];
#pragma unroll
    for (int j = 0; j < 4; ++j) {
      int d = tid + (half * 4 + j) * 256;  // 0..2047
      int f = d >> 3;
      int kpair = d & 7;
      int i = band_of_f(f);
      int kp = (i << 5) + 2 * (f - f0_of_band(i));  // always even
      bool v = (t0 + 2 * kpair < 1000);
      row[j] = 2 * kpair; kps[j] = kp; val[j] = v;
      if (v) {
        xv[j] = xq[f * 500 + kpair];
        ab[j] = sq[kp >> 1];
      }
    }
#pragma unroll
    for (int j = 0; j < 4; ++j) {
      if (val[j]) {
        unsigned int r0 = f2bf(xv[j].x * ab[j].x + ab[j].z);
        unsigned int r1 = f2bf(xv[j].y * ab[j].y + ab[j].w);
        unsigned int r2 = f2bf(xv[j].z * ab[j].x + ab[j].z);
        unsigned int r3 = f2bf(xv[j].w * ab[j].y + ab[j].w);
        *(unsigned int*)&xn[row[j]][kps[j]] = r0 | (r1 << 16);  // kp even
        *(unsigned int*)&xn[row[j] + 1][kps[j]] = r2 | (r3 << 16);
      }
    }
  }
  // tail: f = 256 (band 30, cidx 32/33 -> kp 992), 8 float4 by tid<8
  if (tid < 8 && t0 + 2 * tid < 1000) {
    float4 v = xq[256 * 500 + tid];
    float4 ab = sq[496];  // kp 992
    unsigned int r0 = f2bf(v.x * ab.x + ab.z);
    unsigned int r1 = f2bf(v.y * ab.y + ab.w);
    unsigned int r2 = f2bf(v.z * ab.x + ab.z);
    unsigned int r3 = f2bf(v.w * ab.y + ab.w);
    *(unsigned int*)&xn[2 * tid][992] = r0 | (r1 << 16);
    *(unsigned int*)&xn[2 * tid + 1][992] = r2 | (r3 << 16);
  }
  __syncthreads();

  // Phase 2: MFMAs; wave wv handles bands wv, wv+4, ...; 4 OT per band.
  floatx4 acc[8][4];
#pragma unroll
  for (int it = 0; it < 8; ++it) {
    const int band = wv + it * 4;
    if (band >= 31) break;
    const bool dbl = (band == 30);  // c=34 -> second kstep
    short8 a0 = *(const short8*)&xn[n][(band << 5) + (quad << 3)];
#pragma unroll
    for (int p = 0; p < 4; ++p) {
      const int OT = (qh << 2) | p;
      float bv = bias[it][p];
      floatx4 a = {bv, bv, bv, bv};
      short8 b0 = ((const short8*)wf)[(band * 8 + OT) * 64 + l];
      a = __builtin_amdgcn_mfma_f32_16x16x32_bf16(a0, b0, a, 0, 0, 0);
      if (dbl) {
        short8 a1 = *(const short8*)&xn[n][992 + (quad << 3)];
        short8 b1 = ((const short8*)wf)[(31 * 8 + OT) * 64 + l];
        a = __builtin_amdgcn_mfma_f32_16x16x32_bf16(a1, b1, a, 0, 0, 0);
      }
      acc[it][p] = a;
    }
  }
  __syncthreads();  // all xn reads done; safe to overwrite union

  // Phase 3: four 1-OT passes. Each deposits D fragments into
  // stage[m][n*31 + band] (m = quad*4 + r; D row(m)=quad*4+r, col=lane&15,
  // m89/m91-verified) then stores 16 rows x 496 f32, contiguous in out at
  // uint4 index (b*1000+t)*992 + OT*124 (rows 64B-aligned).
#pragma unroll
  for (int p = 0; p < 4; ++p) {
    if (p) __syncthreads();  // previous pass's store reads done
#pragma unroll
    for (int it = 0; it < 8; ++it) {
      const int band = wv + it * 4;
      if (band >= 31) break;
#pragma unroll
      for (int r = 0; r < 4; ++r)
        stage[(quad << 2) + r][n * 31 + band] = acc[it][p][r];
    }
    __syncthreads();
    const int OT = (qh << 2) | p;
    for (int e = tid; e < 16 * 124; e += 256) {
      int m = e / 124;
      int d = e - m * 124;
      int t = t0 + m;
      if (t < 1000) {
        uint4 v = ((const uint4*)&stage[m][0])[d];
        ((uint4*)out)[(long)(b * 1000 + t) * 992 + OT * 124 + d] = v;
      }
    }
  }
}

extern "C" void kernel_launch(void* const* d_in, const int* in_sizes, int n_in,
                              void* d_out, int out_size, void* d_ws, size_t ws_size,
                              hipStream_t stream) {
  const float* x = (const float*)d_in[0];
  const float* gn_w = (const float*)d_in[1];
  const float* gn_b = (const float*)d_in[2];
  const float* fc_w = (const float*)d_in[3];
  const float* fc_b = (const float*)d_in[4];
  float* out = (float*)d_out;

  float* sAB = (float*)d_ws;                               // 131,072 B
  unsigned short* wf = (unsigned short*)(sAB + 16 * 2048);  // 262,144 B

  prep_kernel<<<560, 256, 0, stream>>>(x, gn_w, gn_b, fc_w, sAB, wf);
  main_kernel<<<dim3(64, 2, 16), 256, 0, stream>>>(x, sAB, wf, fc_b, out);
}

// Round 6
// 307.287 us; speedup vs baseline: 1.0635x; 1.0327x over previous
//
#include <hip/hip_runtime.h>
#include <hip/hip_bf16.h>

// BandSplit on MI355X — round 7.
// R6 post-mortem: qh-halving canceled by occupancy loss (acc[8][4]=128 VGPR
// -> 3 blocks/CU). Lesson: phase-1 redundancy ~= occupancy; win one without
// losing the other. This round: 512-thread blocks, 8 waves x (4 bands x 4 OT)
// -> acc[4][4]=64 VGPR, launch_bounds(512,4) -> 2 blocks/CU = 16 waves/CU
// (same as R4) WITH qh-halved phase-1. LDS 63.5 KB/block (2 fit) -> phase-3
// stages 2 OT per pass => 2 passes, half the epilogue barriers of R6.
//
// ws layout (f32 unless noted):
//   sAB : float[16][2048]   interleaved (a(2j),a(2j+1),s(2j),s(2j+1)) quads,
//                           a = rsigma*gn_w, s = gn_b - mu*rsigma*gn_w,
//                           at K-padded positions (band i -> kp=32i)
//   wf  : ushort[32*8*64*8] fc_w as bf16 in MFMA B-fragment order, 0-padded
// total 393,216 B (unchanged).

typedef short short8 __attribute__((ext_vector_type(8)));
typedef float floatx4 __attribute__((ext_vector_type(4)));

__device__ __forceinline__ unsigned short f2bf(float f) {
  unsigned int u = __float_as_uint(f);
  u = (u + 0x7fffu + ((u >> 16) & 1u)) >> 16;  // RNE
  return (unsigned short)u;
}

// BANDS = [2, 3x10, 8x12, 16x7, 17]; c = 2*band; K padded to 32 per band
// (band 30: c=34 -> ksteps 30 and 31).
__device__ __forceinline__ int band_of_f(int f) {
  if (f < 2) return 0;
  if (f < 32) return 1 + (f - 2) / 3;
  if (f < 128) return 11 + (f - 32) / 8;
  if (f < 240) return 23 + (f - 128) / 16;
  return 30;
}
__device__ __forceinline__ int f0_of_band(int i) {
  if (i == 0) return 0;
  if (i <= 10) return 2 + 3 * (i - 1);
  if (i <= 22) return 32 + 8 * (i - 11);
  if (i <= 29) return 128 + 16 * (i - 23);
  return 240;
}
__device__ __forceinline__ int c_of_band(int i) {
  if (i == 0) return 4;
  if (i <= 10) return 6;
  if (i <= 22) return 16;
  if (i <= 29) return 32;
  return 34;
}
__device__ __forceinline__ int bw_of_band(int i) {
  if (i == 0) return 2;
  if (i <= 10) return 3;
  if (i <= 22) return 8;
  if (i <= 29) return 16;
  return 17;
}

// ---------------------------------------------------------------------------
// Kernel 1 (fused): blocks 0..495 = per-(band,batch) GroupNorm stats folded
// into the packed sAB quads; blocks 496..559 = fc_w (f32) -> bf16 MFMA
// B-fragment order. Independent work, one launch.
// ---------------------------------------------------------------------------
__global__ __launch_bounds__(256) void prep_kernel(
    const float* __restrict__ x,
    const float* __restrict__ gn_w,
    const float* __restrict__ gn_b,
    const float* __restrict__ fc_w,
    float* __restrict__ sAB,
    unsigned short* __restrict__ wf) {
  const int blk = blockIdx.x;
  const int tid = threadIdx.x;
  __shared__ float redS[4], redQ[4];
  __shared__ float musig[2];

  if (blk >= 496) {
    // ---- wprep part: flat short8 index gid = ks*512 + ot*64 + lane;
    // element j = Wp[kp = ks*32 + (lane>>4)*8 + j][o = ot*16 + (lane&15)].
    const int gid = (blk - 496) * 256 + tid;  // 0..16383
    const int ks = gid >> 9;
    const int rem = gid & 511;
    const int ot = rem >> 6;
    const int l = rem & 63;
    const int o = ot * 16 + (l & 15);
    const int kbase = ks * 32 + ((l >> 4) << 3);
    short8 v;
#pragma unroll
    for (int j = 0; j < 8; ++j) {
      int kp = kbase + j;
      int i = (kp >= 960) ? 30 : (kp >> 5);
      int cidx = kp - (i << 5);
      int c = c_of_band(i);
      unsigned short w =
          (cidx < c) ? f2bf(fc_w[(i * 128 + o) * 34 + cidx]) : (unsigned short)0;
      v[j] = (short)w;
    }
    ((short8*)wf)[gid] = v;
    return;
  }

  // ---- stats part
  const int i = blk % 31;  // band
  const int b = blk / 31;  // batch
  const int bw = bw_of_band(i);
  const int f0 = f0_of_band(i);
  // slab: x[b, f0:f0+bw, :, :] -> contiguous bw*2000 f32; start*4 % 16 == 0
  const long start = ((long)(b * 257 + f0)) * 2000;
  const float4* p4 = (const float4*)(x + start);
  const int nchunk = bw * 500;  // 4 f32 per chunk

  float s = 0.f, sq = 0.f;
  int e = tid;
  for (; e + 768 < nchunk; e += 1024) {
    float4 w0 = p4[e];
    float4 w1 = p4[e + 256];
    float4 w2 = p4[e + 512];
    float4 w3 = p4[e + 768];
    s += (w0.x + w0.y + w0.z + w0.w) + (w1.x + w1.y + w1.z + w1.w) +
         (w2.x + w2.y + w2.z + w2.w) + (w3.x + w3.y + w3.z + w3.w);
    sq += (w0.x * w0.x + w0.y * w0.y + w0.z * w0.z + w0.w * w0.w) +
          (w1.x * w1.x + w1.y * w1.y + w1.z * w1.z + w1.w * w1.w) +
          (w2.x * w2.x + w2.y * w2.y + w2.z * w2.z + w2.w * w2.w) +
          (w3.x * w3.x + w3.y * w3.y + w3.z * w3.z + w3.w * w3.w);
  }
  for (; e < nchunk; e += 256) {
    float4 v = p4[e];
    s += v.x + v.y + v.z + v.w;
    sq += v.x * v.x + v.y * v.y + v.z * v.z + v.w * v.w;
  }
#pragma unroll
  for (int off = 32; off > 0; off >>= 1) {
    s += __shfl_down(s, off);
    sq += __shfl_down(sq, off);
  }
  if ((tid & 63) == 0) { redS[tid >> 6] = s; redQ[tid >> 6] = sq; }
  __syncthreads();
  if (tid == 0) {
    float S = redS[0] + redS[1] + redS[2] + redS[3];
    float Q = redQ[0] + redQ[1] + redQ[2] + redQ[3];
    float cnt = (float)(bw * 2000);
    float mu = S / cnt;
    float var = Q / cnt - mu * mu;
    musig[0] = mu;
    musig[1] = rsqrtf(var + 1e-5f);
  }
  __syncthreads();
  const int c = c_of_band(i);
  if (tid < c) {
    float mu = musig[0], rs = musig[1];
    float gw = gn_w[i * 34 + tid];
    float gb = gn_b[i * 34 + tid];
    float a = rs * gw;
    int kp = i * 32 + tid;  // band 30 spills into kstep 31
    // packed quad (a_even, a_odd, s_even, s_odd) at quad index kp>>1
    sAB[(b << 11) + ((kp >> 1) << 2) + (kp & 1)] = a;
    sAB[(b << 11) + ((kp >> 1) << 2) + 2 + (kp & 1)] = gb - mu * a;
  }
}

// ---------------------------------------------------------------------------
// Kernel 2: main. Grid = (tc 64 [63 + 1 pad], qh 2, b 16) x 512 threads.
// 8 waves; wave wv owns bands {wv, wv+8, wv+16, wv+24} x 4 OT -> acc[4][4]
// = 64 VGPR. __launch_bounds__(512,4) -> VGPR cap 128 -> 2 blocks/CU =
// 16 waves/CU (R4 occupancy) with phase-1 built once per o-HALF.
// Phase 1: x (f32) -> normalized bf16 [16][1032] in LDS; packed-sAB float4.
//          512 threads share the build: 4 loads each + tail.
// Phase 2: 4 bands x 4 OT MFMAs per wave; fc_b inline (L2-hot).
// Phase 3: two 2-OT passes: deposit 16x992 f32 into the SAME LDS (union,
//          all MFMAs done), then coalesced dwordx4 stores of 992-f32 runs.
// LDS = 63,488 B -> exactly 2 blocks/CU.
// ---------------------------------------------------------------------------
__global__ __launch_bounds__(512, 4) void main_kernel(
    const float* __restrict__ x,
    const float* __restrict__ sAB,
    const unsigned short* __restrict__ wf,
    const float* __restrict__ fc_b,
    float* __restrict__ out) {
  const int tc = blockIdx.x;  // 0..63 (63 is grid pad)
  const int qh = blockIdx.y;  // 0..1  (o-half)
  const int b = blockIdx.z;   // 0..15
  const int t0 = tc * 16;
  if (t0 >= 1000) return;  // uniform pad-block exit, before any barrier
  const int tid = threadIdx.x;

  __shared__ __align__(16) unsigned char lds_raw[16 * 992 * 4];  // 63,488 B
  unsigned short(*xn)[1032] = (unsigned short(*)[1032])lds_raw;  // 33,024 B
  float(*stage)[992] = (float(*)[992])lds_raw;                   // 63,488 B

  // zero xn (pads must be 0 so MFMA K-padding contributes nothing)
  // 2064 uint4 = 4*512 + 16
  for (int e = tid; e < 2064; e += 512)
    ((uint4*)lds_raw)[e] = make_uint4(0u, 0u, 0u, 0u);
  __syncthreads();

  // Phase 1: x (f32) -> normalized bf16, layout [t_local][kp].
  // float4 element d = 0..2047: f = d>>3, kpair = d&7 -> t = t0 + 2*kpair,
  // covers t and t+1 (t even => never straddles the t=999 edge).
  // Packed sAB: quad (a_e, a_o, s_e, s_o) at index kp>>1 — one float4 load.
  const float4* xq = (const float4*)(x + (long)b * 514000 + (long)t0 * 2);
  const float4* sq = (const float4*)(sAB + (b << 11));
  {
    float4 xv[4], ab[4];
    int row[4], kps[4];
    bool val[4];
#pragma unroll
    for (int j = 0; j < 4; ++j) {
      int d = tid + j * 512;  // 0..2047
      int f = d >> 3;
      int kpair = d & 7;
      int i = band_of_f(f);
      int kp = (i << 5) + 2 * (f - f0_of_band(i));  // always even
      bool v = (t0 + 2 * kpair < 1000);
      row[j] = 2 * kpair; kps[j] = kp; val[j] = v;
      if (v) {
        xv[j] = xq[f * 500 + kpair];
        ab[j] = sq[kp >> 1];
      }
    }
#pragma unroll
    for (int j = 0; j < 4; ++j) {
      if (val[j]) {
        unsigned int r0 = f2bf(xv[j].x * ab[j].x + ab[j].z);
        unsigned int r1 = f2bf(xv[j].y * ab[j].y + ab[j].w);
        unsigned int r2 = f2bf(xv[j].z * ab[j].x + ab[j].z);
        unsigned int r3 = f2bf(xv[j].w * ab[j].y + ab[j].w);
        *(unsigned int*)&xn[row[j]][kps[j]] = r0 | (r1 << 16);  // kp even
        *(unsigned int*)&xn[row[j] + 1][kps[j]] = r2 | (r3 << 16);
      }
    }
  }
  // tail: f = 256 (band 30, cidx 32/33 -> kp 992), 8 float4 by tid<8
  if (tid < 8 && t0 + 2 * tid < 1000) {
    float4 v = xq[256 * 500 + tid];
    float4 ab = sq[496];  // kp 992
    unsigned int r0 = f2bf(v.x * ab.x + ab.z);
    unsigned int r1 = f2bf(v.y * ab.y + ab.w);
    unsigned int r2 = f2bf(v.z * ab.x + ab.z);
    unsigned int r3 = f2bf(v.w * ab.y + ab.w);
    *(unsigned int*)&xn[2 * tid][992] = r0 | (r1 << 16);
    *(unsigned int*)&xn[2 * tid + 1][992] = r2 | (r3 << 16);
  }
  __syncthreads();

  // Phase 2: MFMAs; wave wv handles bands wv, wv+8, wv+16, wv+24; 4 OT each.
  const int wv = tid >> 6;   // 0..7
  const int l = tid & 63;
  const int quad = l >> 4;
  const int n = l & 15;
  floatx4 acc[4][4];
#pragma unroll
  for (int it = 0; it < 4; ++it) {
    const int band = wv + it * 8;
    if (band >= 31) break;
    const bool dbl = (band == 30);  // c=34 -> second kstep
    short8 a0 = *(const short8*)&xn[n][(band << 5) + (quad << 3)];
#pragma unroll
    for (int p = 0; p < 4; ++p) {
      const int OT = (qh << 2) | p;
      float bv = fc_b[band * 128 + (OT << 4) + n];
      floatx4 a = {bv, bv, bv, bv};
      short8 b0 = ((const short8*)wf)[(band * 8 + OT) * 64 + l];
      a = __builtin_amdgcn_mfma_f32_16x16x32_bf16(a0, b0, a, 0, 0, 0);
      if (dbl) {
        short8 a1 = *(const short8*)&xn[n][992 + (quad << 3)];
        short8 b1 = ((const short8*)wf)[(31 * 8 + OT) * 64 + l];
        a = __builtin_amdgcn_mfma_f32_16x16x32_bf16(a1, b1, a, 0, 0, 0);
      }
      acc[it][p] = a;
    }
  }
  __syncthreads();  // all xn reads done; safe to overwrite union

  // Phase 3: two 2-OT passes. Pass p2 deposits D fragments into
  // stage[m][(ot*16 + n)*31 + band] (m = quad*4 + r; D row(m)=quad*4+r,
  // col=lane&15, m89/m91-verified), then stores 16 rows x 992 f32,
  // contiguous in out at uint4 index (b*1000+t)*992 + qh*496 + p2*248.
#pragma unroll
  for (int p2 = 0; p2 < 2; ++p2) {
    if (p2) __syncthreads();  // pass-0 store reads done before overwrite
#pragma unroll
    for (int it = 0; it < 4; ++it) {
      const int band = wv + it * 8;
      if (band >= 31) break;
#pragma unroll
      for (int ot = 0; ot < 2; ++ot) {
        const int col = ((ot << 4) + n) * 31 + band;
#pragma unroll
        for (int r = 0; r < 4; ++r)
          stage[(quad << 2) + r][col] = acc[it][(p2 << 1) | ot][r];
      }
    }
    __syncthreads();
    for (int e = tid; e < 16 * 248; e += 512) {
      int m = e / 248;
      int d = e - m * 248;
      int t = t0 + m;
      if (t < 1000) {
        uint4 v = ((const uint4*)&stage[m][0])[d];
        ((uint4*)out)[(long)(b * 1000 + t) * 992 + qh * 496 + p2 * 248 + d] = v;
      }
    }
  }
}

extern "C" void kernel_launch(void* const* d_in, const int* in_sizes, int n_in,
                              void* d_out, int out_size, void* d_ws, size_t ws_size,
                              hipStream_t stream) {
  const float* x = (const float*)d_in[0];
  const float* gn_w = (const float*)d_in[1];
  const float* gn_b = (const float*)d_in[2];
  const float* fc_w = (const float*)d_in[3];
  const float* fc_b = (const float*)d_in[4];
  float* out = (float*)d_out;

  float* sAB = (float*)d_ws;                               // 131,072 B
  unsigned short* wf = (unsigned short*)(sAB + 16 * 2048);  // 262,144 B

  prep_kernel<<<560, 256, 0, stream>>>(x, gn_w, gn_b, fc_w, sAB, wf);
  main_kernel<<<dim3(64, 2, 16), 512, 0, stream>>>(x, sAB, wf, fc_b, out);
}